// Round 5
// baseline (335.229 us; speedup 1.0000x reference)
//
#include <hip/hip_runtime.h>

#define BATCH 16
#define TFRAMES 2000
#define BINS 513
#define NFFT 1024
#define STEP 256
#define OUT_LEN 512768            // (TFRAMES-1)*STEP + NFFT
#define M_TOTAL (BATCH*TFRAMES)   // 32000
// GEMM carries bins 1..511 only (pairs p=0..510, p=511 zero-pad); DC (bin 0) and
// Nyquist (bin 512) are added exactly in the epilogue: sin==0 there, cos = 1 / (-1)^n.
#define KP 1024                   // halves: 512 pairs, 16 iters of BK=64
#define PAIRS 512
#define WGT (1.0f/512.0f)         // uniform 2/1024 for bins 1..511

typedef _Float16 f16x8 __attribute__((ext_vector_type(8)));
typedef float    f32x4 __attribute__((ext_vector_type(4)));

// ---------------- pack_B (2 MB, cheap; L2-resident during GEMM) ----------------
// B[n][2p] = cos[n][p+1], B[n][2p+1] = sin[n][p+1]; p=511 -> 0.
__global__ __launch_bounds__(256) void pack_B(const float* __restrict__ dcos,
                                              const float* __restrict__ dsin,
                                              unsigned* __restrict__ Bu)
{
    const int idx = blockIdx.x * 256 + threadIdx.x;   // n*PAIRS + p, exact grid
    const int n = idx >> 9;
    const int p = idx & 511;
    float b0 = 0.f, b1 = 0.f;
    if (p < 511) {
        const size_t base = (size_t)n * NFFT + p + 1;
        b0 = dcos[base];
        b1 = dsin[base];
    }
    union { _Float16 h[2]; unsigned u; } pk;
    pk.h[0] = (_Float16)b0;
    pk.h[1] = (_Float16)b1;
    Bu[idx] = pk.u;
}

// ---------------- fused MFMA GEMM (pack_A folded into staging) ----------------
#define BM 128
#define BN 128
#define BK 64    // halves per k-iter = 32 pairs; 16 iters over KP=1024

__device__ __forceinline__ void async_copy16(const void* g, void* l) {
    __builtin_amdgcn_global_load_lds(
        (const __attribute__((address_space(1))) unsigned*)g,
        (__attribute__((address_space(3))) unsigned*)l, 16, 0, 0);
}

// LDS layout (both tiles): [128 rows][8 chunks of 16B], chunk c stored at slot c^(row&7).
// B: global_load_lds (lane-contiguous), swizzle on the global address (r3: 0 conflicts).
// A: fp32 loads -> f16 cvt in regs -> ds_write_b128 at the swizzled slot (dense 16B
//    permutation per wave -> conflict-free).
template<bool USE_FRAMES>
__global__ __launch_bounds__(256, 3) void gemm_fused(const float* __restrict__ sre,
                                                     const float* __restrict__ sim,
                                                     const _Float16* __restrict__ B,
                                                     const float* __restrict__ window,
                                                     _Float16* __restrict__ frames,
                                                     float* __restrict__ out)
{
    __shared__ _Float16 As[BM * BK];   // 16 KB
    __shared__ _Float16 Bs[BN * BK];   // 16 KB

    // XCD-grouping swizzle: keep the 8 n-tiles of one m-slab on one XCD.
    const int raw = blockIdx.x;                    // 0..1999
    const int idx = (raw & 7) * 250 + (raw >> 3);  // bijection
    const int mt = idx >> 3;                       // 0..249
    const int nt = idx & 7;                        // 0..7
    const int m0 = mt * BM;
    const int n0 = nt * BN;

    const int tid  = threadIdx.x;
    const int w    = tid >> 6;         // wave 0..3
    const int lane = tid & 63;
    const int wm   = w & 1;            // wave's 64x64 quadrant
    const int wn   = w >> 1;
    const int row16 = lane & 15;
    const int quad  = lane >> 4;

    // ---- B staging (async, unchanged from r3) ----
    const int srow   = lane >> 3;                    // 0..7
    const int schunk = (lane & 7) ^ srow;            // swizzled chunk for this lane
    const _Float16* gB = B + (size_t)(n0 + w*32 + srow) * KP + schunk * 8;

    // ---- A staging assignment: thread covers 4 chunks: rows arow+32s, chunk col c ----
    const int arow = tid >> 3;                       // 0..31
    const int c    = tid & 7;                        // chunk col 0..7
    // pair index of chunk start (iter-relative): 4c; bin = pair+1
    size_t abase[4];
    #pragma unroll
    for (int s = 0; s < 4; s++)
        abase[s] = (size_t)(m0 + arow + 32*s) * BINS + 1 + 4*c;   // bin offset, fp32 elems

    float are[16], aim[16];            // 4 chunks x 4 bins, prefetched

    // preload iter 0
    #pragma unroll
    for (int s = 0; s < 4; s++)
        #pragma unroll
        for (int j = 0; j < 4; j++) {
            are[s*4+j] = sre[abase[s] + j];
            aim[s*4+j] = sim[abase[s] + j];
        }

    f32x4 acc[4][4] = {};

    for (int it = 0; it < 16; ++it) {
        // B async copies into this iter's LDS (prev trailing barrier guarantees free)
        const int k0 = it * BK;
        #pragma unroll
        for (int t = 0; t < 4; t++)
            async_copy16(gB + (size_t)t*8*KP + k0, Bs + (w*4 + t) * 512);

        // A: cvt + swizzled ds_write_b128 (4 chunks)
        #pragma unroll
        for (int s = 0; s < 4; s++) {
            const int row = arow + 32*s;
            union { _Float16 h[8]; uint4 u; } pk;
            #pragma unroll
            for (int j = 0; j < 4; j++) {
                pk.h[2*j]   = (_Float16)( WGT * are[s*4+j]);
                pk.h[2*j+1] = (_Float16)(-WGT * aim[s*4+j]);
            }
            *(uint4*)&As[row * BK + (c ^ (row & 7)) * 8] = pk.u;
        }

        __syncthreads();               // staging visible (drains vm + lgkm)

        // prefetch iter+1 A into regs (covered by the MFMA phase below)
        if (it < 15) {
            const int poff = (it + 1) * 32;          // pair offset -> fp32 elem offset
            const int binc = poff + 4*c + 1;         // bin of j=0
            #pragma unroll
            for (int s = 0; s < 4; s++)
                #pragma unroll
                for (int j = 0; j < 4; j++) {
                    const bool v = (binc + j) < 512;        // exclude bin 512 (pad pair 511)
                    are[s*4+j] = v ? sre[abase[s] + poff + j] : 0.f;
                    aim[s*4+j] = v ? sim[abase[s] + poff + j] : 0.f;
                }
        }

        // ---- MFMA phase ----
        #pragma unroll
        for (int cc = 0; cc < 2; cc++) {
            f16x8 af[4], bf[4];
            #pragma unroll
            for (int i = 0; i < 4; i++) {
                const int rowA = wm*64 + i*16 + row16;
                const int chA  = (cc*4 + quad) ^ (row16 & 7);
                af[i] = *(const f16x8*)&As[rowA * BK + chA * 8];
            }
            #pragma unroll
            for (int j = 0; j < 4; j++) {
                const int rowB = wn*64 + j*16 + row16;
                const int chB  = (cc*4 + quad) ^ (row16 & 7);
                bf[j] = *(const f16x8*)&Bs[rowB * BK + chB * 8];
            }
            #pragma unroll
            for (int i = 0; i < 4; i++)
                #pragma unroll
                for (int j = 0; j < 4; j++)
                    acc[i][j] = __builtin_amdgcn_mfma_f32_16x16x32_f16(af[i], bf[j], acc[i][j], 0, 0, 0);
        }

        __syncthreads();               // reads done before next iter's overwrite
    }

    // Epilogue. C/D layout: col = lane&15, row = quad*4 + reg.
    // DC/Nyquist exact correction: dc_m(n) = (re[m,0] + (-1)^n re[m,512]) / 1024;
    // n parity == row16 parity (n0, wn*64, j*16 all even).
    const float sgn = (row16 & 1) ? -1.0f : 1.0f;
    #pragma unroll
    for (int j = 0; j < 4; j++) {
        const int n = n0 + wn*64 + j*16 + row16;
        const float win = window[n];
        #pragma unroll
        for (int i = 0; i < 4; i++) {
            const int mrow = m0 + wm*64 + i*16 + quad*4;
            const f32x4 cv = acc[i][j];
            #pragma unroll
            for (int r = 0; r < 4; r++) {
                const int m = mrow + r;
                const float re0   = sre[(size_t)m * BINS];
                const float re512 = sre[(size_t)m * BINS + 512];
                const float dc = (re0 + sgn * re512) * (1.0f/1024.0f);
                const float val = (cv[r] + dc) * win;
                if (USE_FRAMES) {
                    frames[(size_t)m * NFFT + n] = (_Float16)val;
                } else {
                    const int b = m / TFRAMES;
                    const int t = m - b * TFRAMES;
                    atomicAdd(&out[(size_t)b * OUT_LEN + (size_t)t * STEP + n], val);
                }
            }
        }
    }
}

// ---------------- deterministic overlap-add gather (r4, verified) ----------------
#define OLA_G 64096   // OUT_LEN/8
__global__ __launch_bounds__(256) void ola_gather(const _Float16* __restrict__ frames,
                                                  float* __restrict__ out)
{
    const int idx = blockIdx.x * 256 + threadIdx.x;   // b*OLA_G + r, exact grid
    const int b = idx / OLA_G;
    const int r = idx - b * OLA_G;
    const int s0 = r << 3;
    int tlo = (s0 - 768) >> 8;  if (tlo < 0) tlo = 0;
    int thi = s0 >> 8;          if (thi > TFRAMES-1) thi = TFRAMES-1;
    float sum[8] = {};
    for (int t = tlo; t <= thi; ++t) {
        const f16x8 f = *(const f16x8*)&frames[((size_t)b * TFRAMES + t) * NFFT + (s0 - (t << 8))];
        #pragma unroll
        for (int i = 0; i < 8; i++) sum[i] += (float)f[i];
    }
    f32x4* o = (f32x4*)(out + (size_t)b * OUT_LEN + s0);
    o[0] = (f32x4){sum[0], sum[1], sum[2], sum[3]};
    o[1] = (f32x4){sum[4], sum[5], sum[6], sum[7]};
}

// ---------------- round-1 fp32 fallback (known-correct) ----------------
#define MT 64
#define NT 64
#define KT 16
#define PAD 4
__global__ __launch_bounds__(256) void istft_gemm_ola_f32(
    const float* __restrict__ sre, const float* __restrict__ sim,
    const float* __restrict__ dcos, const float* __restrict__ dsin,
    const float* __restrict__ window, float* __restrict__ out)
{
    __shared__ float As_re[KT][MT + PAD];
    __shared__ float As_im[KT][MT + PAD];
    __shared__ float Bs_c[KT][NT + PAD];
    __shared__ float Bs_s[KT][NT + PAD];
    const int ntile = blockIdx.x & 15;
    const int mtile = blockIdx.x >> 4;
    const int m0 = mtile * MT, n0 = ntile * NT;
    const int tid = threadIdx.x;
    const int tx = tid & 15, ty = tid >> 4;
    const int lcol = tid & 15, lrow = tid >> 4;
    float acc[4][4] = {};
    for (int k0 = 0; k0 < BINS; k0 += KT) {
        const int k = k0 + lcol;
        const bool kvalid = (k < BINS);
        const float w = kvalid ? ((k == 0 || k == 512) ? (1.0f/1024.0f) : (2.0f/1024.0f)) : 0.0f;
        #pragma unroll
        for (int i = 0; i < 4; i++) {
            const int m = m0 + lrow + i*16;
            const size_t base = (size_t)m * BINS + k;
            As_re[lcol][lrow + i*16] = kvalid ?  w * sre[base] : 0.0f;
            As_im[lcol][lrow + i*16] = kvalid ? -w * sim[base] : 0.0f;
        }
        #pragma unroll
        for (int i = 0; i < 4; i++) {
            const int n = n0 + lrow + i*16;
            const size_t base = (size_t)n * NFFT + k;
            Bs_c[lcol][lrow + i*16] = kvalid ? dcos[base] : 0.0f;
            Bs_s[lcol][lrow + i*16] = kvalid ? dsin[base] : 0.0f;
        }
        __syncthreads();
        #pragma unroll
        for (int kk = 0; kk < KT; kk++) {
            const float4 ar = *(const float4*)&As_re[kk][ty*4];
            const float4 ai = *(const float4*)&As_im[kk][ty*4];
            const float4 bc = *(const float4*)&Bs_c[kk][tx*4];
            const float4 bs = *(const float4*)&Bs_s[kk][tx*4];
            const float a_r[4] = {ar.x, ar.y, ar.z, ar.w};
            const float a_i[4] = {ai.x, ai.y, ai.z, ai.w};
            const float b_c[4] = {bc.x, bc.y, bc.z, bc.w};
            const float b_s[4] = {bs.x, bs.y, bs.z, bs.w};
            #pragma unroll
            for (int i = 0; i < 4; i++)
                #pragma unroll
                for (int j = 0; j < 4; j++)
                    acc[i][j] += a_r[i]*b_c[j] + a_i[i]*b_s[j];
        }
        __syncthreads();
    }
    #pragma unroll
    for (int i = 0; i < 4; i++) {
        const int m = m0 + ty*4 + i;
        const int b = m / TFRAMES;
        const int t = m - b * TFRAMES;
        const size_t obase = (size_t)b * OUT_LEN + (size_t)t * STEP;
        #pragma unroll
        for (int j = 0; j < 4; j++) {
            const int n = n0 + tx*4 + j;
            atomicAdd(&out[obase + n], acc[i][j] * window[n]);
        }
    }
}

// ---------------- launch ----------------
extern "C" void kernel_launch(void* const* d_in, const int* in_sizes, int n_in,
                              void* d_out, int out_size, void* d_ws, size_t ws_size,
                              hipStream_t stream) {
    const float* sre    = (const float*)d_in[0];
    const float* sim    = (const float*)d_in[1];
    const float* dcos   = (const float*)d_in[2];
    const float* dsin   = (const float*)d_in[3];
    const float* window = (const float*)d_in[4];
    float* out = (float*)d_out;

    const size_t WS_B      = (size_t)NFFT * KP * sizeof(_Float16);       //  2,097,152
    const size_t WS_FRAMES = (size_t)M_TOTAL * NFFT * sizeof(_Float16);  // 65,536,000

    if (ws_size >= WS_B) {
        _Float16* Bpk    = (_Float16*)d_ws;
        _Float16* frames = (_Float16*)((char*)d_ws + WS_B);
        const bool have_frames = (ws_size >= WS_B + WS_FRAMES);

        pack_B<<<(NFFT * PAIRS) / 256, 256, 0, stream>>>(dcos, dsin, (unsigned*)Bpk);

        const int grid = (M_TOTAL / BM) * (NFFT / BN);   // 250 * 8 = 2000
        if (have_frames) {
            gemm_fused<true><<<grid, 256, 0, stream>>>(sre, sim, Bpk, window, frames, out);
            ola_gather<<<(BATCH * OUT_LEN) / 2048, 256, 0, stream>>>(frames, out);
        } else {
            hipMemsetAsync(out, 0, (size_t)out_size * sizeof(float), stream);
            gemm_fused<false><<<grid, 256, 0, stream>>>(sre, sim, Bpk, window, nullptr, out);
        }
    } else {
        hipMemsetAsync(out, 0, (size_t)out_size * sizeof(float), stream);
        const int grid = (M_TOTAL / MT) * (NFFT / NT);
        istft_gemm_ola_f32<<<grid, 256, 0, stream>>>(sre, sim, dcos, dsin, window, out);
    }
}

// Round 6
// 254.606 us; speedup vs baseline: 1.3167x; 1.3167x over previous
//
#include <hip/hip_runtime.h>

#define BATCH 16
#define TFRAMES 2000
#define BINS 513
#define NFFT 1024
#define STEP 256
#define OUT_LEN 512768            // (TFRAMES-1)*STEP + NFFT
#define M_TOTAL (BATCH*TFRAMES)   // 32000
// K layout (pairs, 2 halves each): pair 0 = DC/Nyquist trick:
//   A[m][0]=(re[m,0]/1024, re[m,512]/1024), B[n][0]=(1, (-1)^n)
//   -> dot = (re0 + (-1)^n re512)/1024, exactly the bin-0 + bin-512 term.
// pairs p=1..511: A=(re[m,p]/512, -im[m,p]/512), B=(cos[n,p], sin[n,p]).
// KP = 2*512 = 1024 halves: 16 iters of BK=64, zero waste.
#define KP 1024
#define PAIRS 512
#define JPACK 128                 // uint4 groups (4 pairs) per packed A row

typedef _Float16 f16x8 __attribute__((ext_vector_type(8)));
typedef float    f32x4 __attribute__((ext_vector_type(4)));

// ---------------- pack kernels ----------------
__global__ __launch_bounds__(256) void pack_A(const float* __restrict__ sre,
                                              const float* __restrict__ sim,
                                              uint4* __restrict__ Au)
{
    const int idx = blockIdx.x * 256 + threadIdx.x;   // m*JPACK + j, exact grid
    const int m = idx >> 7;
    const int j = idx & 127;
    const int k0 = j * 4;                             // pair index of group start
    const size_t base = (size_t)m * BINS + k0;        // bin==pair for j>=1 lanes
    union { _Float16 h[8]; uint4 u; } pk;
    if (j == 0) {
        // pairs 0..3: pair0 = DC/Nyquist, pairs 1..3 = bins 1..3
        const float re0   = sre[(size_t)m * BINS];
        const float re512 = sre[(size_t)m * BINS + 512];
        pk.h[0] = (_Float16)(re0   * (1.0f/1024.0f));
        pk.h[1] = (_Float16)(re512 * (1.0f/1024.0f));
        #pragma unroll
        for (int i = 1; i < 4; i++) {
            pk.h[2*i]   = (_Float16)( sre[base + i] * (1.0f/512.0f));
            pk.h[2*i+1] = (_Float16)(-sim[base + i] * (1.0f/512.0f));
        }
    } else {
        // bins 4j..4j+3, all within 4..511 -> no guards
        #pragma unroll
        for (int i = 0; i < 4; i++) {
            pk.h[2*i]   = (_Float16)( sre[base + i] * (1.0f/512.0f));
            pk.h[2*i+1] = (_Float16)(-sim[base + i] * (1.0f/512.0f));
        }
    }
    Au[idx] = pk.u;
}

__global__ __launch_bounds__(256) void pack_B(const float* __restrict__ dcos,
                                              const float* __restrict__ dsin,
                                              unsigned* __restrict__ Bu)
{
    const int idx = blockIdx.x * 256 + threadIdx.x;   // n*PAIRS + p, exact grid
    const int n = idx >> 9;
    const int p = idx & 511;
    float b0, b1;
    if (p == 0) {
        b0 = 1.0f;
        b1 = (n & 1) ? -1.0f : 1.0f;                  // cos[n][512] = (-1)^n
    } else {
        const size_t base = (size_t)n * NFFT + p;
        b0 = dcos[base];
        b1 = dsin[base];
    }
    union { _Float16 h[2]; unsigned u; } pk;
    pk.h[0] = (_Float16)b0;
    pk.h[1] = (_Float16)b1;
    Bu[idx] = pk.u;
}

// ---------------- MFMA GEMM (r3/r4-proven structure, KP=1024) ----------------
#define BM 128
#define BN 128
#define BK 64    // halves per k-iter = 32 pairs; 16 iters over KP=1024

__device__ __forceinline__ void async_copy16(const void* g, void* l) {
    __builtin_amdgcn_global_load_lds(
        (const __attribute__((address_space(1))) unsigned*)g,
        (__attribute__((address_space(3))) unsigned*)l, 16, 0, 0);
}

// LDS layout: [128 rows][8 chunks of 16B], chunk c stored at slot c^(row&7).
// Swizzle applied on the GLOBAL address side (global_load_lds is lane-contiguous).
// Verified round 3/4: SQ_LDS_BANK_CONFLICT == 0.
template<bool USE_FRAMES>
__global__ __launch_bounds__(256, 3) void gemm_f16(const _Float16* __restrict__ A,
                                                   const _Float16* __restrict__ B,
                                                   const float* __restrict__ window,
                                                   _Float16* __restrict__ frames,
                                                   float* __restrict__ out)
{
    __shared__ _Float16 As[BM * BK];   // 16 KB
    __shared__ _Float16 Bs[BN * BK];   // 16 KB

    // XCD-grouping swizzle: keep the 8 n-tiles of one m-slab on one XCD.
    const int raw = blockIdx.x;                    // 0..1999
    const int idx = (raw & 7) * 250 + (raw >> 3);  // bijection
    const int mt = idx >> 3;                       // 0..249
    const int nt = idx & 7;                        // 0..7
    const int m0 = mt * BM;
    const int n0 = nt * BN;

    const int tid  = threadIdx.x;
    const int w    = tid >> 6;         // wave 0..3
    const int lane = tid & 63;
    const int wm   = w & 1;            // wave's 64x64 quadrant
    const int wn   = w >> 1;
    const int row16 = lane & 15;
    const int quad  = lane >> 4;

    // staging addresses
    const int srow   = lane >> 3;                    // 0..7
    const int schunk = (lane & 7) ^ srow;            // swizzled chunk for this lane
    const _Float16* gA = A + (size_t)(m0 + w*32 + srow) * KP + schunk * 8;
    const _Float16* gB = B + (size_t)(n0 + w*32 + srow) * KP + schunk * 8;

    f32x4 acc[4][4] = {};

    for (int k0 = 0; k0 < KP; k0 += BK) {
        #pragma unroll
        for (int t = 0; t < 4; t++) {
            async_copy16(gA + (size_t)t*8*KP + k0, As + (w*4 + t) * 512);
            async_copy16(gB + (size_t)t*8*KP + k0, Bs + (w*4 + t) * 512);
        }
        __syncthreads();               // drain staging

        #pragma unroll
        for (int c = 0; c < 2; c++) {
            f16x8 af[4], bf[4];
            #pragma unroll
            for (int i = 0; i < 4; i++) {
                const int rowA = wm*64 + i*16 + row16;
                const int chA  = (c*4 + quad) ^ (row16 & 7);
                af[i] = *(const f16x8*)&As[rowA * BK + chA * 8];
            }
            #pragma unroll
            for (int j = 0; j < 4; j++) {
                const int rowB = wn*64 + j*16 + row16;
                const int chB  = (c*4 + quad) ^ (row16 & 7);
                bf[j] = *(const f16x8*)&Bs[rowB * BK + chB * 8];
            }
            #pragma unroll
            for (int i = 0; i < 4; i++)
                #pragma unroll
                for (int j = 0; j < 4; j++)
                    acc[i][j] = __builtin_amdgcn_mfma_f32_16x16x32_f16(af[i], bf[j], acc[i][j], 0, 0, 0);
        }

        __syncthreads();               // all waves done reading before overwrite
    }

    // Epilogue. C/D layout: col = lane&15, row = quad*4 + reg.
    #pragma unroll
    for (int j = 0; j < 4; j++) {
        const int n = n0 + wn*64 + j*16 + row16;
        const float win = window[n];
        #pragma unroll
        for (int i = 0; i < 4; i++) {
            const int mrow = m0 + wm*64 + i*16 + quad*4;
            const f32x4 c = acc[i][j];
            if (USE_FRAMES) {
                #pragma unroll
                for (int r = 0; r < 4; r++)
                    frames[(size_t)(mrow + r) * NFFT + n] = (_Float16)(c[r] * win);
            } else {
                #pragma unroll
                for (int r = 0; r < 4; r++) {
                    const int m = mrow + r;
                    const int b = m / TFRAMES;
                    const int t = m - b * TFRAMES;
                    atomicAdd(&out[(size_t)b * OUT_LEN + (size_t)t * STEP + n], c[r] * win);
                }
            }
        }
    }
}

// ---------------- deterministic overlap-add gather (r4, verified) ----------------
#define OLA_G 64096   // OUT_LEN/8
__global__ __launch_bounds__(256) void ola_gather(const _Float16* __restrict__ frames,
                                                  float* __restrict__ out)
{
    const int idx = blockIdx.x * 256 + threadIdx.x;   // b*OLA_G + r, exact grid
    const int b = idx / OLA_G;
    const int r = idx - b * OLA_G;
    const int s0 = r << 3;
    int tlo = (s0 - 768) >> 8;  if (tlo < 0) tlo = 0;
    int thi = s0 >> 8;          if (thi > TFRAMES-1) thi = TFRAMES-1;
    float sum[8] = {};
    for (int t = tlo; t <= thi; ++t) {
        const f16x8 f = *(const f16x8*)&frames[((size_t)b * TFRAMES + t) * NFFT + (s0 - (t << 8))];
        #pragma unroll
        for (int i = 0; i < 8; i++) sum[i] += (float)f[i];
    }
    f32x4* o = (f32x4*)(out + (size_t)b * OUT_LEN + s0);
    o[0] = (f32x4){sum[0], sum[1], sum[2], sum[3]};
    o[1] = (f32x4){sum[4], sum[5], sum[6], sum[7]};
}

// ---------------- round-1 fp32 fallback (known-correct) ----------------
#define MT 64
#define NT 64
#define KT 16
#define PAD 4
__global__ __launch_bounds__(256) void istft_gemm_ola_f32(
    const float* __restrict__ sre, const float* __restrict__ sim,
    const float* __restrict__ dcos, const float* __restrict__ dsin,
    const float* __restrict__ window, float* __restrict__ out)
{
    __shared__ float As_re[KT][MT + PAD];
    __shared__ float As_im[KT][MT + PAD];
    __shared__ float Bs_c[KT][NT + PAD];
    __shared__ float Bs_s[KT][NT + PAD];
    const int ntile = blockIdx.x & 15;
    const int mtile = blockIdx.x >> 4;
    const int m0 = mtile * MT, n0 = ntile * NT;
    const int tid = threadIdx.x;
    const int tx = tid & 15, ty = tid >> 4;
    const int lcol = tid & 15, lrow = tid >> 4;
    float acc[4][4] = {};
    for (int k0 = 0; k0 < BINS; k0 += KT) {
        const int k = k0 + lcol;
        const bool kvalid = (k < BINS);
        const float w = kvalid ? ((k == 0 || k == 512) ? (1.0f/1024.0f) : (2.0f/1024.0f)) : 0.0f;
        #pragma unroll
        for (int i = 0; i < 4; i++) {
            const int m = m0 + lrow + i*16;
            const size_t base = (size_t)m * BINS + k;
            As_re[lcol][lrow + i*16] = kvalid ?  w * sre[base] : 0.0f;
            As_im[lcol][lrow + i*16] = kvalid ? -w * sim[base] : 0.0f;
        }
        #pragma unroll
        for (int i = 0; i < 4; i++) {
            const int n = n0 + lrow + i*16;
            const size_t base = (size_t)n * NFFT + k;
            Bs_c[lcol][lrow + i*16] = kvalid ? dcos[base] : 0.0f;
            Bs_s[lcol][lrow + i*16] = kvalid ? dsin[base] : 0.0f;
        }
        __syncthreads();
        #pragma unroll
        for (int kk = 0; kk < KT; kk++) {
            const float4 ar = *(const float4*)&As_re[kk][ty*4];
            const float4 ai = *(const float4*)&As_im[kk][ty*4];
            const float4 bc = *(const float4*)&Bs_c[kk][tx*4];
            const float4 bs = *(const float4*)&Bs_s[kk][tx*4];
            const float a_r[4] = {ar.x, ar.y, ar.z, ar.w};
            const float a_i[4] = {ai.x, ai.y, ai.z, ai.w};
            const float b_c[4] = {bc.x, bc.y, bc.z, bc.w};
            const float b_s[4] = {bs.x, bs.y, bs.z, bs.w};
            #pragma unroll
            for (int i = 0; i < 4; i++)
                #pragma unroll
                for (int j = 0; j < 4; j++)
                    acc[i][j] += a_r[i]*b_c[j] + a_i[i]*b_s[j];
        }
        __syncthreads();
    }
    #pragma unroll
    for (int i = 0; i < 4; i++) {
        const int m = m0 + ty*4 + i;
        const int b = m / TFRAMES;
        const int t = m - b * TFRAMES;
        const size_t obase = (size_t)b * OUT_LEN + (size_t)t * STEP;
        #pragma unroll
        for (int j = 0; j < 4; j++) {
            const int n = n0 + tx*4 + j;
            atomicAdd(&out[obase + n], acc[i][j] * window[n]);
        }
    }
}

// ---------------- launch ----------------
extern "C" void kernel_launch(void* const* d_in, const int* in_sizes, int n_in,
                              void* d_out, int out_size, void* d_ws, size_t ws_size,
                              hipStream_t stream) {
    const float* sre    = (const float*)d_in[0];
    const float* sim    = (const float*)d_in[1];
    const float* dcos   = (const float*)d_in[2];
    const float* dsin   = (const float*)d_in[3];
    const float* window = (const float*)d_in[4];
    float* out = (float*)d_out;

    const size_t WS_A      = (size_t)M_TOTAL * KP * sizeof(_Float16);    // 65,536,000
    const size_t WS_B      = (size_t)NFFT    * KP * sizeof(_Float16);    //  2,097,152
    const size_t WS_FRAMES = (size_t)M_TOTAL * NFFT * sizeof(_Float16);  // 65,536,000

    if (ws_size >= WS_A + WS_B) {
        _Float16* Apk    = (_Float16*)d_ws;
        _Float16* Bpk    = (_Float16*)((char*)d_ws + WS_A);
        _Float16* frames = (_Float16*)((char*)d_ws + WS_A + WS_B);
        const bool have_frames = (ws_size >= WS_A + WS_B + WS_FRAMES);

        pack_A<<<(M_TOTAL * JPACK) / 256, 256, 0, stream>>>(sre, sim, (uint4*)Apk);
        pack_B<<<(NFFT * PAIRS) / 256, 256, 0, stream>>>(dcos, dsin, (unsigned*)Bpk);

        const int grid = (M_TOTAL / BM) * (NFFT / BN);   // 250 * 8 = 2000
        if (have_frames) {
            gemm_f16<true><<<grid, 256, 0, stream>>>(Apk, Bpk, window, frames, out);
            ola_gather<<<(BATCH * OUT_LEN) / 2048, 256, 0, stream>>>(frames, out);
        } else {
            hipMemsetAsync(out, 0, (size_t)out_size * sizeof(float), stream);
            gemm_f16<false><<<grid, 256, 0, stream>>>(Apk, Bpk, window, nullptr, out);
        }
    } else {
        hipMemsetAsync(out, 0, (size_t)out_size * sizeof(float), stream);
        const int grid = (M_TOTAL / MT) * (NFFT / NT);
        istft_gemm_ola_f32<<<grid, 256, 0, stream>>>(sre, sim, dcos, dsin, window, out);
    }
}